// Round 8
// baseline (201.130 us; speedup 1.0000x reference)
//
#include <hip/hip_runtime.h>
#include <cstdint>
#include <cstddef>

// ---------------------------------------------------------------------------
// ChatGPTAttention: x[2,2048,1024] -> QKV proj -> causal MHA (16 heads, dk=64)
//                   -> O proj. bf16 MFMA pipeline, fp32 accumulate.
// Q is pre-scaled by 1/8 in the QKV-GEMM epilogue (cols < 1024).
// LESSONS: (R5) LDS row stride must be a multiple of 8 ushorts (16B) or
// ds_read_b128 leaves the fast path (3.7x). (R6) DMA-staged GEMM LDS needs
// the XOR source-swizzle to kill 8-way b128 conflicts. (R7) attn was
// LDS-pipe-bound (~430 LDS cyc vs 87 MFMA cyc per trip-wave) -> v6
// restructure: 32 q/wave + S^T QK + transposed PV to halve LDS per q-row.
// ---------------------------------------------------------------------------

typedef __attribute__((ext_vector_type(8))) short bf16x8;   // MFMA A/B frag
typedef __attribute__((ext_vector_type(4))) float f32x4;    // MFMA C/D frag
typedef __attribute__((ext_vector_type(4))) unsigned int u32x4;   // 16B copy
typedef __attribute__((ext_vector_type(4))) unsigned short u16x4; // 8B store
typedef __attribute__((ext_vector_type(8))) unsigned short u16x8; // 16B store

__device__ __forceinline__ unsigned short f2b(float f) {  // RNE f32->bf16
  unsigned int u = __float_as_uint(f);
  u = u + 0x7FFFu + ((u >> 16) & 1u);
  return (unsigned short)(u >> 16);
}
__device__ __forceinline__ unsigned short f2b_trunc(float f) {  // truncate
  return (unsigned short)(__float_as_uint(f) >> 16);
}

// async global->LDS DMA, 16B per lane; LDS dest = wave base + lane*16
__device__ __forceinline__ void gl_lds16(const unsigned short* g, unsigned short* s) {
  __builtin_amdgcn_global_load_lds((const __attribute__((address_space(1))) void*)g,
                                   (__attribute__((address_space(3))) void*)s, 16, 0, 0);
}

// ---------------- fp32 -> bf16, all three inputs in one launch -------------
__global__ __launch_bounds__(256) void cvt_all(const float* __restrict__ x,
                                               const float* __restrict__ wq,
                                               const float* __restrict__ wo,
                                               unsigned short* __restrict__ xb,
                                               unsigned short* __restrict__ wqb,
                                               unsigned short* __restrict__ wob) {
  const int bid = blockIdx.x;
  const float* in;
  unsigned short* out;
  int base;
  if (bid < 4096)      { in = x;  out = xb;  base = bid; }
  else if (bid < 7168) { in = wq; out = wqb; base = bid - 4096; }
  else                 { in = wo; out = wob; base = bid - 7168; }
  const int idx = (base * 256 + threadIdx.x) * 4;
  f32x4 v = *(const f32x4*)(in + idx);
  u16x4 r;
  r[0] = f2b(v[0]); r[1] = f2b(v[1]); r[2] = f2b(v[2]); r[3] = f2b(v[3]);
  *(u16x4*)(out + idx) = r;
}

// ---------------- GEMM: C[M,N] = (A[M,K] * W[N,K]^T + bias) * colscale -----
// 128x128 tile, BK=64, 4 waves 2x2, 64x64/wave. DMA staging + XOR swizzle:
// LDS slot (row r, chunk s) holds global chunk s^(r&7); reads XOR back.
__global__ __launch_bounds__(256) void gemm_bt(const unsigned short* __restrict__ A,
                                               const unsigned short* __restrict__ W,
                                               const float* __restrict__ bias,
                                               unsigned short* __restrict__ Cb,
                                               int M, int N, int K, int qcols) {
  __shared__ unsigned short As[128 * 64];
  __shared__ unsigned short Bs[128 * 64];
  const int tid  = threadIdx.x;
  const int lane = tid & 63;
  const int w    = tid >> 6;
  const int wy   = w >> 1, wx = w & 1;
  const int l15  = lane & 15, quad = lane >> 4;
  const int xr   = l15 & 7;
  const int m0 = blockIdx.y * 128, n0 = blockIdx.x * 128;

  const unsigned short* gA[4];
  const unsigned short* gB[4];
  unsigned short* sA[4];
  unsigned short* sB[4];
#pragma unroll
  for (int p = 0; p < 4; ++p) {
    const int c = tid + p * 256;
    const int r = c >> 3;
    const int srcc = (c & 7) ^ (r & 7);
    gA[p] = A + (size_t)(m0 + r) * K + srcc * 8;
    gB[p] = W + (size_t)(n0 + r) * K + srcc * 8;
    sA[p] = &As[c * 8];
    sB[p] = &Bs[c * 8];
  }

  f32x4 acc[4][4];
#pragma unroll
  for (int i = 0; i < 4; ++i)
#pragma unroll
    for (int j = 0; j < 4; ++j) acc[i][j] = (f32x4){0.f, 0.f, 0.f, 0.f};

  for (int kt = 0; kt < K; kt += 64) {
#pragma unroll
    for (int p = 0; p < 4; ++p) {
      gl_lds16(gA[p] + kt, sA[p]);
      gl_lds16(gB[p] + kt, sB[p]);
    }
    __syncthreads();
#pragma unroll
    for (int kc = 0; kc < 2; ++kc) {
      bf16x8 af[4], bfr[4];
#pragma unroll
      for (int i = 0; i < 4; ++i)
        af[i] = *(const bf16x8*)&As[(wy * 64 + i * 16 + l15) * 64 + ((kc * 4 + quad) ^ xr) * 8];
#pragma unroll
      for (int j = 0; j < 4; ++j)
        bfr[j] = *(const bf16x8*)&Bs[(wx * 64 + j * 16 + l15) * 64 + ((kc * 4 + quad) ^ xr) * 8];
#pragma unroll
      for (int i = 0; i < 4; ++i)
#pragma unroll
        for (int j = 0; j < 4; ++j)
          acc[i][j] = __builtin_amdgcn_mfma_f32_16x16x32_bf16(af[i], bfr[j], acc[i][j], 0, 0, 0);
    }
    __syncthreads();
  }

#pragma unroll
  for (int i = 0; i < 4; ++i) {
    const int row = m0 + wy * 64 + i * 16 + quad * 4;
#pragma unroll
    for (int j = 0; j < 4; ++j) {
      const int col = n0 + wx * 64 + j * 16 + l15;
      const float bv = bias[col];
      const float sc = (col < qcols) ? 0.125f : 1.0f;
#pragma unroll
      for (int r = 0; r < 4; ++r)
        Cb[(size_t)(row + r) * N + col] = f2b((acc[i][j][r] + bv) * sc);
    }
  }
}

// ---------------- GEMM 64x128 tile, fp32 out (O-projection) ----------------
// Grid 8x64 = 512 blocks = 2 blocks/CU. BK=64 + XOR swizzle as gemm_bt.
__global__ __launch_bounds__(256) void gemm_bt64(const unsigned short* __restrict__ A,
                                                 const unsigned short* __restrict__ W,
                                                 const float* __restrict__ bias,
                                                 float* __restrict__ Cf,
                                                 int M, int N, int K) {
  __shared__ unsigned short As[64 * 64];
  __shared__ unsigned short Bs[128 * 64];
  const int tid  = threadIdx.x;
  const int lane = tid & 63;
  const int w    = tid >> 6;
  const int wy   = w >> 1, wx = w & 1;
  const int l15  = lane & 15, quad = lane >> 4;
  const int xr   = l15 & 7;
  const int m0 = blockIdx.y * 64, n0 = blockIdx.x * 128;

  const unsigned short* gA[2];
  const unsigned short* gB[4];
  unsigned short* sA[2];
  unsigned short* sB[4];
#pragma unroll
  for (int p = 0; p < 2; ++p) {
    const int c = tid + p * 256;
    const int r = c >> 3;
    const int srcc = (c & 7) ^ (r & 7);
    gA[p] = A + (size_t)(m0 + r) * K + srcc * 8;
    sA[p] = &As[c * 8];
  }
#pragma unroll
  for (int p = 0; p < 4; ++p) {
    const int c = tid + p * 256;
    const int r = c >> 3;
    const int srcc = (c & 7) ^ (r & 7);
    gB[p] = W + (size_t)(n0 + r) * K + srcc * 8;
    sB[p] = &Bs[c * 8];
  }

  f32x4 acc[2][4];
#pragma unroll
  for (int i = 0; i < 2; ++i)
#pragma unroll
    for (int j = 0; j < 4; ++j) acc[i][j] = (f32x4){0.f, 0.f, 0.f, 0.f};

  for (int kt = 0; kt < K; kt += 64) {
#pragma unroll
    for (int p = 0; p < 2; ++p) gl_lds16(gA[p] + kt, sA[p]);
#pragma unroll
    for (int p = 0; p < 4; ++p) gl_lds16(gB[p] + kt, sB[p]);
    __syncthreads();
#pragma unroll
    for (int kc = 0; kc < 2; ++kc) {
      bf16x8 af[2], bfr[4];
#pragma unroll
      for (int i = 0; i < 2; ++i)
        af[i] = *(const bf16x8*)&As[(wy * 32 + i * 16 + l15) * 64 + ((kc * 4 + quad) ^ xr) * 8];
#pragma unroll
      for (int j = 0; j < 4; ++j)
        bfr[j] = *(const bf16x8*)&Bs[(wx * 64 + j * 16 + l15) * 64 + ((kc * 4 + quad) ^ xr) * 8];
#pragma unroll
      for (int i = 0; i < 2; ++i)
#pragma unroll
        for (int j = 0; j < 4; ++j)
          acc[i][j] = __builtin_amdgcn_mfma_f32_16x16x32_bf16(af[i], bfr[j], acc[i][j], 0, 0, 0);
    }
    __syncthreads();
  }

#pragma unroll
  for (int i = 0; i < 2; ++i) {
    const int row = m0 + wy * 32 + i * 16 + quad * 4;
#pragma unroll
    for (int j = 0; j < 4; ++j) {
      const int col = n0 + wx * 64 + j * 16 + l15;
      const float bv = bias[col];
#pragma unroll
      for (int r = 0; r < 4; ++r)
        Cf[(size_t)(row + r) * N + col] = acc[i][j][r] + bv;
    }
  }
}

// ---------------- V transpose: qkv V-part -> vt[(bh*64+d)][s] --------------
__global__ __launch_bounds__(256) void transpose_v(const unsigned short* __restrict__ qkv,
                                                   unsigned short* __restrict__ vt) {
  __shared__ unsigned short tile[64][72];
  const int tid = threadIdx.x;
  const int bh = blockIdx.y, b = bh >> 4, h = bh & 15;
  const int s0 = blockIdx.x * 64;
  const int i = tid >> 2;
  const int j = (tid & 3) * 16;
  const unsigned short* g = qkv + (size_t)(b * 2048 + s0 + i) * 3072 + 2048 + h * 64 + j;
  *(u32x4*)&tile[i][j]     = *(const u32x4*)g;
  *(u32x4*)&tile[i][j + 8] = *(const u32x4*)(g + 8);
  __syncthreads();
  const int d  = tid >> 2;
  const int sj = (tid & 3) * 16;
  u16x8 o0, o1;
#pragma unroll
  for (int k = 0; k < 8; ++k) { o0[k] = tile[sj + k][d]; o1[k] = tile[sj + 8 + k][d]; }
  unsigned short* gout = vt + (size_t)(bh * 64 + d) * 2048 + s0 + sj;
  *(u16x8*)gout       = o0;
  *(u16x8*)(gout + 8) = o1;
}

// ---------------- flash attention v6 ---------------------------------------
// Block = 128 q rows (4 waves x 32 q), grid (x=bh 32, y=16 qtiles) = 512
// blocks (XCD = bh%8 -> K/V stream XCD-L2-resident; qt = 15-y -> LPT).
// Per wave: 2 q-frags (qa, qb=qa+16) as MFMA *B* operands.
//  QK computed as S^T = K * Q^T (A=K from LDS, B=Q regs): C-layout puts
//   q in l15, kv in quad*4+reg -> 4 consecutive kv per reg quad -> P written
//   as packed ds_write_b64 (8/trip vs 32 scalar b16).
//  PV computed as O^T = V^T * P^T (A=V^T frags, same Vs reads; B=P read
//   contiguously at pbuf[q][kv0..]); l via ones-A MFMA (all rows = l[q]).
//  Epilogue: lane holds 4 consecutive d -> packed u16x4 global stores.
// K/V frag reads amortized over 32 q rows: per trip-wave 36 MFMA vs 20 b128
// reads (was 18 vs 18). Low-q waves do a few fully-masked trips (exp->0).
// LDS 55.3 KB -> 2 blocks/CU. Stride 72 (16B-aligned, R5 lesson).
__global__ __launch_bounds__(256, 2) void attn_fwd(const unsigned short* __restrict__ qkv,
                                                   const unsigned short* __restrict__ vt,
                                                   unsigned short* __restrict__ o) {
  __shared__ unsigned short Ks[2][64 * 72];
  __shared__ unsigned short Vs[2][64 * 72];
  __shared__ unsigned short pbuf[4][32 * 72];
  const int tid  = threadIdx.x;
  const int lane = tid & 63;
  const int w    = tid >> 6;
  const int l15  = lane & 15, quad = lane >> 4;
  const int bh = blockIdx.x, b = bh >> 4, h = bh & 15;
  const int qt = 15 - (int)blockIdx.y;  // LPT order
  const int q0 = qt * 128;
  const int qa = q0 + w * 32;           // wave's first 16-q tile
  const int qb = qa + 16;               // wave's second 16-q tile
  const int T = 2 * qt + 2;             // kv tiles to cover q0+127

  const int srow = tid >> 2;
  const int scol = (tid & 3) * 16;
  const unsigned short* gK = qkv + (size_t)(b * 2048 + srow) * 3072 + 1024 + h * 64 + scol;
  const unsigned short* gV = vt + (size_t)(bh * 64 + srow) * 2048 + scol;

  // Q B-frags: B[n=q(l15)][k=d(quad*8+j)], two 16-q tiles x two 32-k halves
  const unsigned short* qra = qkv + (size_t)(b * 2048 + qa + l15) * 3072 + h * 64;
  const unsigned short* qrb = qkv + (size_t)(b * 2048 + qb + l15) * 3072 + h * 64;
  const bf16x8 bq[2][2] = {
    { *(const bf16x8*)(qra + quad * 8), *(const bf16x8*)(qra + 32 + quad * 8) },
    { *(const bf16x8*)(qrb + quad * 8), *(const bf16x8*)(qrb + 32 + quad * 8) } };

  bf16x8 vones;
#pragma unroll
  for (int k = 0; k < 8; ++k) vones[k] = (short)0x3F80;  // bf16 1.0

  f32x4 acc[2][4];   // [q-tile][d-tile] — O^T C-layout: col=q(l15), row=d
#pragma unroll
  for (int i = 0; i < 2; ++i)
#pragma unroll
    for (int j = 0; j < 4; ++j) acc[i][j] = (f32x4){0.f, 0.f, 0.f, 0.f};
  f32x4 accL[2] = {(f32x4){0.f, 0.f, 0.f, 0.f}, (f32x4){0.f, 0.f, 0.f, 0.f}};

  unsigned short* P = pbuf[w];  // [q 0..31][kv 0..63], stride 72

  {  // prologue: stage trip 0 into buf 0
    u32x4 k0 = *(const u32x4*)gK, k1 = *(const u32x4*)(gK + 8);
    u32x4 v0 = *(const u32x4*)gV, v1 = *(const u32x4*)(gV + 8);
    unsigned short* sK = &Ks[0][srow * 72 + scol];
    unsigned short* sV = &Vs[0][srow * 72 + scol];
    *(u32x4*)sK = k0; *(u32x4*)(sK + 8) = k1;
    *(u32x4*)sV = v0; *(u32x4*)(sV + 8) = v1;
  }

  for (int t = 0; t < T; ++t) {
    __syncthreads();  // buf(t&1) staged; WAR-protects other buf rewrite
    const int cur = t & 1;
    const unsigned short* Kc = Ks[cur];
    const unsigned short* Vc = Vs[cur];
    u32x4 nk0, nk1, nv0, nv1;
    const bool more = (t + 1 < T);
    if (more) {
      const size_t ko = (size_t)(t + 1) * 64 * 3072;
      const int vo = (t + 1) * 64;
      nk0 = *(const u32x4*)(gK + ko); nk1 = *(const u32x4*)(gK + ko + 8);
      nv0 = *(const u32x4*)(gV + vo); nv1 = *(const u32x4*)(gV + vo + 8);
    }
    const int kv0 = t * 64;

    // ---- S^T[kv][q] = K Q^T : A=K-frag (m=kv), B=Q-frag (n=q) ----
    f32x4 st[2][4];  // [q-tile][kv-16-block n]; lane: col q=l15, row kv=n*16+quad*4+r
#pragma unroll
    for (int n = 0; n < 4; ++n) {
      const bf16x8 kA0 = *(const bf16x8*)&Kc[(n * 16 + l15) * 72 + quad * 8];
      const bf16x8 kA1 = *(const bf16x8*)&Kc[(n * 16 + l15) * 72 + 32 + quad * 8];
      f32x4 z0 = (f32x4){0.f, 0.f, 0.f, 0.f};
      z0 = __builtin_amdgcn_mfma_f32_16x16x32_bf16(kA0, bq[0][0], z0, 0, 0, 0);
      z0 = __builtin_amdgcn_mfma_f32_16x16x32_bf16(kA1, bq[0][1], z0, 0, 0, 0);
      st[0][n] = z0;
      f32x4 z1 = (f32x4){0.f, 0.f, 0.f, 0.f};
      z1 = __builtin_amdgcn_mfma_f32_16x16x32_bf16(kA0, bq[1][0], z1, 0, 0, 0);
      z1 = __builtin_amdgcn_mfma_f32_16x16x32_bf16(kA1, bq[1][1], z1, 0, 0, 0);
      st[1][n] = z1;
    }
    // ---- mask (edge only) + exp + packed P write ----
#pragma unroll
    for (int tq = 0; tq < 2; ++tq) {
      const int qbase = tq ? qb : qa;
      if (kv0 + 63 > qbase) {
        const int qrow = qbase + l15;
#pragma unroll
        for (int n = 0; n < 4; ++n)
#pragma unroll
          for (int r = 0; r < 4; ++r)
            if (kv0 + n * 16 + quad * 4 + r > qrow) st[tq][n][r] = -1e30f;
      }
#pragma unroll
      for (int n = 0; n < 4; ++n) {
#pragma unroll
        for (int r = 0; r < 4; ++r) st[tq][n][r] = __expf(st[tq][n][r]);
        u16x4 pw;
        pw[0] = f2b_trunc(st[tq][n][0]); pw[1] = f2b_trunc(st[tq][n][1]);
        pw[2] = f2b_trunc(st[tq][n][2]); pw[3] = f2b_trunc(st[tq][n][3]);
        *(u16x4*)&P[(tq * 16 + l15) * 72 + n * 16 + quad * 4] = pw;
      }
    }
    // ---- V^T A-frags (shared across both q-tiles) ----
    bf16x8 av[4][2];
#pragma unroll
    for (int j = 0; j < 4; ++j) {
      av[j][0] = *(const bf16x8*)&Vc[(j * 16 + l15) * 72 + quad * 8];
      av[j][1] = *(const bf16x8*)&Vc[(j * 16 + l15) * 72 + 32 + quad * 8];
    }
    // ---- O^T += V^T P^T ; l += 1 P^T (per q-tile) ----
#pragma unroll
    for (int tq = 0; tq < 2; ++tq) {
      const bf16x8 bp0 = *(const bf16x8*)&P[(tq * 16 + l15) * 72 + quad * 8];
      const bf16x8 bp1 = *(const bf16x8*)&P[(tq * 16 + l15) * 72 + 32 + quad * 8];
      accL[tq] = __builtin_amdgcn_mfma_f32_16x16x32_bf16(vones, bp0, accL[tq], 0, 0, 0);
      accL[tq] = __builtin_amdgcn_mfma_f32_16x16x32_bf16(vones, bp1, accL[tq], 0, 0, 0);
#pragma unroll
      for (int j = 0; j < 4; ++j) {
        acc[tq][j] = __builtin_amdgcn_mfma_f32_16x16x32_bf16(av[j][0], bp0, acc[tq][j], 0, 0, 0);
        acc[tq][j] = __builtin_amdgcn_mfma_f32_16x16x32_bf16(av[j][1], bp1, acc[tq][j], 0, 0, 0);
      }
    }
    // ---- write prefetched tile to other buffer (WAR-safe past barrier) ----
    if (more) {
      unsigned short* sK = &Ks[cur ^ 1][srow * 72 + scol];
      unsigned short* sV = &Vs[cur ^ 1][srow * 72 + scol];
      *(u32x4*)sK = nk0; *(u32x4*)(sK + 8) = nk1;
      *(u32x4*)sV = nv0; *(u32x4*)(sV + 8) = nv1;
    }
  }
  // ---- epilogue: O = O^T^T / l ; lane holds q=l15, d=j*16+quad*4+r ----
#pragma unroll
  for (int tq = 0; tq < 2; ++tq) {
    const int qrow = (tq ? qb : qa) + l15;
    const float inv = 1.0f / accL[tq][0];  // all rows of accL equal l[q]
    unsigned short* orow = o + (size_t)(b * 2048 + qrow) * 1024 + h * 64;
#pragma unroll
    for (int j = 0; j < 4; ++j) {
      u16x4 ov;
      ov[0] = f2b(acc[tq][j][0] * inv); ov[1] = f2b(acc[tq][j][1] * inv);
      ov[2] = f2b(acc[tq][j][2] * inv); ov[3] = f2b(acc[tq][j][3] * inv);
      *(u16x4*)(orow + j * 16 + quad * 4) = ov;
    }
  }
}

// ---------------------------------------------------------------------------
extern "C" void kernel_launch(void* const* d_in, const int* in_sizes, int n_in,
                              void* d_out, int out_size, void* d_ws, size_t ws_size,
                              hipStream_t stream) {
  const float* x       = (const float*)d_in[0];
  // d_in[1] = mask: causal tril by construction; implemented analytically.
  const float* w_qkv_w = (const float*)d_in[2];
  const float* w_qkv_b = (const float*)d_in[3];
  const float* w_o_w   = (const float*)d_in[4];
  const float* w_o_b   = (const float*)d_in[5];
  float* out = (float*)d_out;

  unsigned short* ws    = (unsigned short*)d_ws;
  unsigned short* xb    = ws;                                  // 4096*1024
  unsigned short* wqb   = xb   + (size_t)4096 * 1024;          // 3072*1024
  unsigned short* wob   = wqb  + (size_t)3072 * 1024;          // 1024*1024
  unsigned short* qkvb  = wob  + (size_t)1024 * 1024;          // 4096*3072
  unsigned short* vtb   = qkvb + (size_t)4096 * 3072;          // 2048*2048
  unsigned short* attnb = vtb  + (size_t)2048 * 2048;          // 4096*1024

  cvt_all<<<8192, 256, 0, stream>>>(x, w_qkv_w, w_o_w, xb, wqb, wob);
  gemm_bt<<<dim3(24, 32), 256, 0, stream>>>(xb, wqb, w_qkv_b, qkvb, 4096, 3072, 1024, 1024);
  transpose_v<<<dim3(32, 32), 256, 0, stream>>>(qkvb, vtb);
  attn_fwd<<<dim3(32, 16), 256, 0, stream>>>(qkvb, vtb, attnb);
  gemm_bt64<<<dim3(8, 64), 256, 0, stream>>>(attnb, wob, w_o_b, out, 4096, 1024, 1024);
}

// Round 9
// 196.062 us; speedup vs baseline: 1.0258x; 1.0258x over previous
//
#include <hip/hip_runtime.h>
#include <cstdint>
#include <cstddef>

// ---------------------------------------------------------------------------
// ChatGPTAttention: x[2,2048,1024] -> QKV proj -> causal MHA (16 heads, dk=64)
//                   -> O proj. bf16 MFMA pipeline, fp32 accumulate.
// Q is pre-scaled by 1/8 in the QKV-GEMM epilogue (cols < 1024).
// LESSONS: (R5) LDS row stride must be a multiple of 8 ushorts (16B) or
// ds_read_b128 leaves the fast path (3.7x). (R6) DMA-staged GEMM LDS needs
// the XOR source-swizzle to kill 8-way b128 conflicts (R8: confirmed, 3.15M
// conflicts -> 0). (R8) the 2-barrier K-loop serializes DMA latency per iter
// (issue -> drain -> compute): GEMM wall ~ iters x latency, pipes ~idle.
// R9: double-buffer the DMA across the barrier (issue t+1 after barrier,
// drain at NEXT barrier -> latency overlaps compute of tile t).
// ---------------------------------------------------------------------------

typedef __attribute__((ext_vector_type(8))) short bf16x8;   // MFMA A/B frag
typedef __attribute__((ext_vector_type(4))) float f32x4;    // MFMA C/D frag
typedef __attribute__((ext_vector_type(4))) unsigned int u32x4;   // 16B copy
typedef __attribute__((ext_vector_type(4))) unsigned short u16x4; // 8B store
typedef __attribute__((ext_vector_type(8))) unsigned short u16x8; // 16B store

__device__ __forceinline__ unsigned short f2b(float f) {  // RNE f32->bf16
  unsigned int u = __float_as_uint(f);
  u = u + 0x7FFFu + ((u >> 16) & 1u);
  return (unsigned short)(u >> 16);
}
__device__ __forceinline__ unsigned short f2b_trunc(float f) {  // truncate
  return (unsigned short)(__float_as_uint(f) >> 16);
}

// async global->LDS DMA, 16B per lane; LDS dest = wave base + lane*16
__device__ __forceinline__ void gl_lds16(const unsigned short* g, unsigned short* s) {
  __builtin_amdgcn_global_load_lds((const __attribute__((address_space(1))) void*)g,
                                   (__attribute__((address_space(3))) void*)s, 16, 0, 0);
}

// ---------------- fp32 -> bf16, all three inputs in one launch -------------
__global__ __launch_bounds__(256) void cvt_all(const float* __restrict__ x,
                                               const float* __restrict__ wq,
                                               const float* __restrict__ wo,
                                               unsigned short* __restrict__ xb,
                                               unsigned short* __restrict__ wqb,
                                               unsigned short* __restrict__ wob) {
  const int bid = blockIdx.x;
  const float* in;
  unsigned short* out;
  int base;
  if (bid < 4096)      { in = x;  out = xb;  base = bid; }
  else if (bid < 7168) { in = wq; out = wqb; base = bid - 4096; }
  else                 { in = wo; out = wob; base = bid - 7168; }
  const int idx = (base * 256 + threadIdx.x) * 4;
  f32x4 v = *(const f32x4*)(in + idx);
  u16x4 r;
  r[0] = f2b(v[0]); r[1] = f2b(v[1]); r[2] = f2b(v[2]); r[3] = f2b(v[3]);
  *(u16x4*)(out + idx) = r;
}

// ---------------- GEMM: C[M,N] = (A[M,K] * W[N,K]^T + bias) * colscale -----
// 128x128 tile, BK=64, 4 waves 2x2, 64x64/wave. DMA staging + XOR swizzle.
// R9: double-buffered LDS; per iter: barrier -> issue DMA(t+1 -> other buf)
// -> ds_read frags(cur) -> MFMA. The next barrier's vmcnt(0) drain lands
// AFTER a full compute block, so DMA latency is hidden.
__global__ __launch_bounds__(256) void gemm_bt(const unsigned short* __restrict__ A,
                                               const unsigned short* __restrict__ W,
                                               const float* __restrict__ bias,
                                               unsigned short* __restrict__ Cb,
                                               int M, int N, int K, int qcols) {
  __shared__ unsigned short As[2][128 * 64];
  __shared__ unsigned short Bs[2][128 * 64];
  const int tid  = threadIdx.x;
  const int lane = tid & 63;
  const int w    = tid >> 6;
  const int wy   = w >> 1, wx = w & 1;
  const int l15  = lane & 15, quad = lane >> 4;
  const int xr   = l15 & 7;
  const int m0 = blockIdx.y * 128, n0 = blockIdx.x * 128;

  const unsigned short* gA[4];
  const unsigned short* gB[4];
  int off[4];
#pragma unroll
  for (int p = 0; p < 4; ++p) {
    const int c = tid + p * 256;
    const int r = c >> 3;
    const int srcc = (c & 7) ^ (r & 7);
    gA[p] = A + (size_t)(m0 + r) * K + srcc * 8;
    gB[p] = W + (size_t)(n0 + r) * K + srcc * 8;
    off[p] = c * 8;
  }

  f32x4 acc[4][4];
#pragma unroll
  for (int i = 0; i < 4; ++i)
#pragma unroll
    for (int j = 0; j < 4; ++j) acc[i][j] = (f32x4){0.f, 0.f, 0.f, 0.f};

  // prologue: stage tile 0 into buf 0
#pragma unroll
  for (int p = 0; p < 4; ++p) {
    gl_lds16(gA[p], &As[0][off[p]]);
    gl_lds16(gB[p], &Bs[0][off[p]]);
  }

  const int NIT = K >> 6;
  for (int it = 0; it < NIT; ++it) {
    __syncthreads();  // drains DMA for buf(it&1); other buf's reads done
    const int cur = it & 1;
    if (it + 1 < NIT) {  // issue next-tile DMA early; drained at NEXT barrier
      const int kt = (it + 1) << 6;
#pragma unroll
      for (int p = 0; p < 4; ++p) {
        gl_lds16(gA[p] + kt, &As[cur ^ 1][off[p]]);
        gl_lds16(gB[p] + kt, &Bs[cur ^ 1][off[p]]);
      }
    }
    const unsigned short* Ac = As[cur];
    const unsigned short* Bc = Bs[cur];
#pragma unroll
    for (int kc = 0; kc < 2; ++kc) {
      bf16x8 af[4], bfr[4];
#pragma unroll
      for (int i = 0; i < 4; ++i)
        af[i] = *(const bf16x8*)&Ac[(wy * 64 + i * 16 + l15) * 64 + ((kc * 4 + quad) ^ xr) * 8];
#pragma unroll
      for (int j = 0; j < 4; ++j)
        bfr[j] = *(const bf16x8*)&Bc[(wx * 64 + j * 16 + l15) * 64 + ((kc * 4 + quad) ^ xr) * 8];
#pragma unroll
      for (int i = 0; i < 4; ++i)
#pragma unroll
        for (int j = 0; j < 4; ++j)
          acc[i][j] = __builtin_amdgcn_mfma_f32_16x16x32_bf16(af[i], bfr[j], acc[i][j], 0, 0, 0);
    }
  }

#pragma unroll
  for (int i = 0; i < 4; ++i) {
    const int row = m0 + wy * 64 + i * 16 + quad * 4;
#pragma unroll
    for (int j = 0; j < 4; ++j) {
      const int col = n0 + wx * 64 + j * 16 + l15;
      const float bv = bias[col];
      const float sc = (col < qcols) ? 0.125f : 1.0f;
#pragma unroll
      for (int r = 0; r < 4; ++r)
        Cb[(size_t)(row + r) * N + col] = f2b((acc[i][j][r] + bv) * sc);
    }
  }
}

// ---------------- GEMM 64x128 tile, fp32 out (O-projection) ----------------
// Grid 8x64 = 512 blocks. R9: same double-buffered DMA pipeline (LDS 48 KB
// -> 3 blocks/CU).
__global__ __launch_bounds__(256) void gemm_bt64(const unsigned short* __restrict__ A,
                                                 const unsigned short* __restrict__ W,
                                                 const float* __restrict__ bias,
                                                 float* __restrict__ Cf,
                                                 int M, int N, int K) {
  __shared__ unsigned short As[2][64 * 64];
  __shared__ unsigned short Bs[2][128 * 64];
  const int tid  = threadIdx.x;
  const int lane = tid & 63;
  const int w    = tid >> 6;
  const int wy   = w >> 1, wx = w & 1;
  const int l15  = lane & 15, quad = lane >> 4;
  const int xr   = l15 & 7;
  const int m0 = blockIdx.y * 64, n0 = blockIdx.x * 128;

  const unsigned short* gA[2];
  const unsigned short* gB[4];
  int offA[2], offB[4];
#pragma unroll
  for (int p = 0; p < 2; ++p) {
    const int c = tid + p * 256;
    const int r = c >> 3;
    const int srcc = (c & 7) ^ (r & 7);
    gA[p] = A + (size_t)(m0 + r) * K + srcc * 8;
    offA[p] = c * 8;
  }
#pragma unroll
  for (int p = 0; p < 4; ++p) {
    const int c = tid + p * 256;
    const int r = c >> 3;
    const int srcc = (c & 7) ^ (r & 7);
    gB[p] = W + (size_t)(n0 + r) * K + srcc * 8;
    offB[p] = c * 8;
  }

  f32x4 acc[2][4];
#pragma unroll
  for (int i = 0; i < 2; ++i)
#pragma unroll
    for (int j = 0; j < 4; ++j) acc[i][j] = (f32x4){0.f, 0.f, 0.f, 0.f};

#pragma unroll
  for (int p = 0; p < 2; ++p) gl_lds16(gA[p], &As[0][offA[p]]);
#pragma unroll
  for (int p = 0; p < 4; ++p) gl_lds16(gB[p], &Bs[0][offB[p]]);

  const int NIT = K >> 6;
  for (int it = 0; it < NIT; ++it) {
    __syncthreads();
    const int cur = it & 1;
    if (it + 1 < NIT) {
      const int kt = (it + 1) << 6;
#pragma unroll
      for (int p = 0; p < 2; ++p) gl_lds16(gA[p] + kt, &As[cur ^ 1][offA[p]]);
#pragma unroll
      for (int p = 0; p < 4; ++p) gl_lds16(gB[p] + kt, &Bs[cur ^ 1][offB[p]]);
    }
    const unsigned short* Ac = As[cur];
    const unsigned short* Bc = Bs[cur];
#pragma unroll
    for (int kc = 0; kc < 2; ++kc) {
      bf16x8 af[2], bfr[4];
#pragma unroll
      for (int i = 0; i < 2; ++i)
        af[i] = *(const bf16x8*)&Ac[(wy * 32 + i * 16 + l15) * 64 + ((kc * 4 + quad) ^ xr) * 8];
#pragma unroll
      for (int j = 0; j < 4; ++j)
        bfr[j] = *(const bf16x8*)&Bc[(wx * 64 + j * 16 + l15) * 64 + ((kc * 4 + quad) ^ xr) * 8];
#pragma unroll
      for (int i = 0; i < 2; ++i)
#pragma unroll
        for (int j = 0; j < 4; ++j)
          acc[i][j] = __builtin_amdgcn_mfma_f32_16x16x32_bf16(af[i], bfr[j], acc[i][j], 0, 0, 0);
    }
  }

#pragma unroll
  for (int i = 0; i < 2; ++i) {
    const int row = m0 + wy * 32 + i * 16 + quad * 4;
#pragma unroll
    for (int j = 0; j < 4; ++j) {
      const int col = n0 + wx * 64 + j * 16 + l15;
      const float bv = bias[col];
#pragma unroll
      for (int r = 0; r < 4; ++r)
        Cf[(size_t)(row + r) * N + col] = acc[i][j][r] + bv;
    }
  }
}

// ---------------- V transpose: qkv V-part -> vt[(bh*64+d)][s] --------------
__global__ __launch_bounds__(256) void transpose_v(const unsigned short* __restrict__ qkv,
                                                   unsigned short* __restrict__ vt) {
  __shared__ unsigned short tile[64][72];
  const int tid = threadIdx.x;
  const int bh = blockIdx.y, b = bh >> 4, h = bh & 15;
  const int s0 = blockIdx.x * 64;
  const int i = tid >> 2;
  const int j = (tid & 3) * 16;
  const unsigned short* g = qkv + (size_t)(b * 2048 + s0 + i) * 3072 + 2048 + h * 64 + j;
  *(u32x4*)&tile[i][j]     = *(const u32x4*)g;
  *(u32x4*)&tile[i][j + 8] = *(const u32x4*)(g + 8);
  __syncthreads();
  const int d  = tid >> 2;
  const int sj = (tid & 3) * 16;
  u16x8 o0, o1;
#pragma unroll
  for (int k = 0; k < 8; ++k) { o0[k] = tile[sj + k][d]; o1[k] = tile[sj + 8 + k][d]; }
  unsigned short* gout = vt + (size_t)(bh * 64 + d) * 2048 + s0 + sj;
  *(u16x8*)gout       = o0;
  *(u16x8*)(gout + 8) = o1;
}

// ---------------- flash attention v7 ---------------------------------------
// v6 structure (32 q/wave, S^T=KQ^T, O^T=V^T P^T) with pbuf HALVED: the two
// 16-q tiles are processed sequentially through one 16x72 per-wave P buffer
// (in-wave DS ordering makes the WAR safe, no barrier). LDS 45 KB -> 3
// blocks/CU (was 2 at 55 KB — v6's LDS win was eaten by the occupancy drop).
__global__ __launch_bounds__(256, 3) void attn_fwd(const unsigned short* __restrict__ qkv,
                                                   const unsigned short* __restrict__ vt,
                                                   unsigned short* __restrict__ o) {
  __shared__ unsigned short Ks[2][64 * 72];
  __shared__ unsigned short Vs[2][64 * 72];
  __shared__ unsigned short pbuf[4][16 * 72];
  const int tid  = threadIdx.x;
  const int lane = tid & 63;
  const int w    = tid >> 6;
  const int l15  = lane & 15, quad = lane >> 4;
  const int bh = blockIdx.x, b = bh >> 4, h = bh & 15;
  const int qt = 15 - (int)blockIdx.y;  // LPT order
  const int q0 = qt * 128;
  const int qa = q0 + w * 32;
  const int qb = qa + 16;
  const int T = 2 * qt + 2;

  const int srow = tid >> 2;
  const int scol = (tid & 3) * 16;
  const unsigned short* gK = qkv + (size_t)(b * 2048 + srow) * 3072 + 1024 + h * 64 + scol;
  const unsigned short* gV = vt + (size_t)(bh * 64 + srow) * 2048 + scol;

  // Q B-frags: B[n=q(l15)][k=d(quad*8+j)]
  const unsigned short* qra = qkv + (size_t)(b * 2048 + qa + l15) * 3072 + h * 64;
  const unsigned short* qrb = qkv + (size_t)(b * 2048 + qb + l15) * 3072 + h * 64;
  const bf16x8 bq[2][2] = {
    { *(const bf16x8*)(qra + quad * 8), *(const bf16x8*)(qra + 32 + quad * 8) },
    { *(const bf16x8*)(qrb + quad * 8), *(const bf16x8*)(qrb + 32 + quad * 8) } };

  bf16x8 vones;
#pragma unroll
  for (int k = 0; k < 8; ++k) vones[k] = (short)0x3F80;  // bf16 1.0

  f32x4 acc[2][4];   // [q-tile][d-tile] — O^T C-layout: col=q(l15), row=d
#pragma unroll
  for (int i = 0; i < 2; ++i)
#pragma unroll
    for (int j = 0; j < 4; ++j) acc[i][j] = (f32x4){0.f, 0.f, 0.f, 0.f};
  f32x4 accL[2] = {(f32x4){0.f, 0.f, 0.f, 0.f}, (f32x4){0.f, 0.f, 0.f, 0.f}};

  unsigned short* P = pbuf[w];  // [q 0..15][kv 0..63], stride 72

  {  // prologue: stage trip 0 into buf 0
    u32x4 k0 = *(const u32x4*)gK, k1 = *(const u32x4*)(gK + 8);
    u32x4 v0 = *(const u32x4*)gV, v1 = *(const u32x4*)(gV + 8);
    unsigned short* sK = &Ks[0][srow * 72 + scol];
    unsigned short* sV = &Vs[0][srow * 72 + scol];
    *(u32x4*)sK = k0; *(u32x4*)(sK + 8) = k1;
    *(u32x4*)sV = v0; *(u32x4*)(sV + 8) = v1;
  }

  for (int t = 0; t < T; ++t) {
    __syncthreads();  // buf(t&1) staged; WAR-protects other buf rewrite
    const int cur = t & 1;
    const unsigned short* Kc = Ks[cur];
    const unsigned short* Vc = Vs[cur];
    u32x4 nk0, nk1, nv0, nv1;
    const bool more = (t + 1 < T);
    if (more) {
      const size_t ko = (size_t)(t + 1) * 64 * 3072;
      const int vo = (t + 1) * 64;
      nk0 = *(const u32x4*)(gK + ko); nk1 = *(const u32x4*)(gK + ko + 8);
      nv0 = *(const u32x4*)(gV + vo); nv1 = *(const u32x4*)(gV + vo + 8);
    }
    const int kv0 = t * 64;

    // ---- S^T[kv][q] = K Q^T for BOTH q-tiles (K-frags transient) ----
    f32x4 st[2][4];
#pragma unroll
    for (int n = 0; n < 4; ++n) {
      const bf16x8 kA0 = *(const bf16x8*)&Kc[(n * 16 + l15) * 72 + quad * 8];
      const bf16x8 kA1 = *(const bf16x8*)&Kc[(n * 16 + l15) * 72 + 32 + quad * 8];
      f32x4 z0 = (f32x4){0.f, 0.f, 0.f, 0.f};
      z0 = __builtin_amdgcn_mfma_f32_16x16x32_bf16(kA0, bq[0][0], z0, 0, 0, 0);
      z0 = __builtin_amdgcn_mfma_f32_16x16x32_bf16(kA1, bq[0][1], z0, 0, 0, 0);
      st[0][n] = z0;
      f32x4 z1 = (f32x4){0.f, 0.f, 0.f, 0.f};
      z1 = __builtin_amdgcn_mfma_f32_16x16x32_bf16(kA0, bq[1][0], z1, 0, 0, 0);
      z1 = __builtin_amdgcn_mfma_f32_16x16x32_bf16(kA1, bq[1][1], z1, 0, 0, 0);
      st[1][n] = z1;
    }
    // ---- V^T A-frags (shared across both q-tiles) ----
    bf16x8 av[4][2];
#pragma unroll
    for (int j = 0; j < 4; ++j) {
      av[j][0] = *(const bf16x8*)&Vc[(j * 16 + l15) * 72 + quad * 8];
      av[j][1] = *(const bf16x8*)&Vc[(j * 16 + l15) * 72 + 32 + quad * 8];
    }
    // ---- per q-tile: mask+exp -> P (shared 16x72 buffer) -> PV ----
#pragma unroll
    for (int tq = 0; tq < 2; ++tq) {
      const int qbase = tq ? qb : qa;
      if (kv0 + 63 > qbase) {
        const int qrow = qbase + l15;
#pragma unroll
        for (int n = 0; n < 4; ++n)
#pragma unroll
          for (int r = 0; r < 4; ++r)
            if (kv0 + n * 16 + quad * 4 + r > qrow) st[tq][n][r] = -1e30f;
      }
#pragma unroll
      for (int n = 0; n < 4; ++n) {
#pragma unroll
        for (int r = 0; r < 4; ++r) st[tq][n][r] = __expf(st[tq][n][r]);
        u16x4 pw;
        pw[0] = f2b_trunc(st[tq][n][0]); pw[1] = f2b_trunc(st[tq][n][1]);
        pw[2] = f2b_trunc(st[tq][n][2]); pw[3] = f2b_trunc(st[tq][n][3]);
        // WAR vs tq=0's reads: same-wave DS ops are in-order -> safe
        *(u16x4*)&P[l15 * 72 + n * 16 + quad * 4] = pw;
      }
      const bf16x8 bp0 = *(const bf16x8*)&P[l15 * 72 + quad * 8];
      const bf16x8 bp1 = *(const bf16x8*)&P[l15 * 72 + 32 + quad * 8];
      accL[tq] = __builtin_amdgcn_mfma_f32_16x16x32_bf16(vones, bp0, accL[tq], 0, 0, 0);
      accL[tq] = __builtin_amdgcn_mfma_f32_16x16x32_bf16(vones, bp1, accL[tq], 0, 0, 0);
#pragma unroll
      for (int j = 0; j < 4; ++j) {
        acc[tq][j] = __builtin_amdgcn_mfma_f32_16x16x32_bf16(av[j][0], bp0, acc[tq][j], 0, 0, 0);
        acc[tq][j] = __builtin_amdgcn_mfma_f32_16x16x32_bf16(av[j][1], bp1, acc[tq][j], 0, 0, 0);
      }
    }
    // ---- write prefetched tile to other buffer (WAR-safe past barrier) ----
    if (more) {
      unsigned short* sK = &Ks[cur ^ 1][srow * 72 + scol];
      unsigned short* sV = &Vs[cur ^ 1][srow * 72 + scol];
      *(u32x4*)sK = nk0; *(u32x4*)(sK + 8) = nk1;
      *(u32x4*)sV = nv0; *(u32x4*)(sV + 8) = nv1;
    }
  }
  // ---- epilogue: O = O^T^T / l ; lane holds q=l15, d=j*16+quad*4+r ----
#pragma unroll
  for (int tq = 0; tq < 2; ++tq) {
    const int qrow = (tq ? qb : qa) + l15;
    const float inv = 1.0f / accL[tq][0];  // all rows of accL equal l[q]
    unsigned short* orow = o + (size_t)(b * 2048 + qrow) * 1024 + h * 64;
#pragma unroll
    for (int j = 0; j < 4; ++j) {
      u16x4 ov;
      ov[0] = f2b(acc[tq][j][0] * inv); ov[1] = f2b(acc[tq][j][1] * inv);
      ov[2] = f2b(acc[tq][j][2] * inv); ov[3] = f2b(acc[tq][j][3] * inv);
      *(u16x4*)(orow + j * 16 + quad * 4) = ov;
    }
  }
}

// ---------------------------------------------------------------------------
extern "C" void kernel_launch(void* const* d_in, const int* in_sizes, int n_in,
                              void* d_out, int out_size, void* d_ws, size_t ws_size,
                              hipStream_t stream) {
  const float* x       = (const float*)d_in[0];
  // d_in[1] = mask: causal tril by construction; implemented analytically.
  const float* w_qkv_w = (const float*)d_in[2];
  const float* w_qkv_b = (const float*)d_in[3];
  const float* w_o_w   = (const float*)d_in[4];
  const float* w_o_b   = (const float*)d_in[5];
  float* out = (float*)d_out;

  unsigned short* ws    = (unsigned short*)d_ws;
  unsigned short* xb    = ws;                                  // 4096*1024
  unsigned short* wqb   = xb   + (size_t)4096 * 1024;          // 3072*1024
  unsigned short* wob   = wqb  + (size_t)3072 * 1024;          // 1024*1024
  unsigned short* qkvb  = wob  + (size_t)1024 * 1024;          // 4096*3072
  unsigned short* vtb   = qkvb + (size_t)4096 * 3072;          // 2048*2048
  unsigned short* attnb = vtb  + (size_t)2048 * 2048;          // 4096*1024

  cvt_all<<<8192, 256, 0, stream>>>(x, w_qkv_w, w_o_w, xb, wqb, wob);
  gemm_bt<<<dim3(24, 32), 256, 0, stream>>>(xb, wqb, w_qkv_b, qkvb, 4096, 3072, 1024, 1024);
  transpose_v<<<dim3(32, 32), 256, 0, stream>>>(qkvb, vtb);
  attn_fwd<<<dim3(32, 16), 256, 0, stream>>>(qkvb, vtb, attnb);
  gemm_bt64<<<dim3(8, 64), 256, 0, stream>>>(attnb, wob, w_o_b, out, 4096, 1024, 1024);
}